// Round 1
// baseline (784.656 us; speedup 1.0000x reference)
//
#include <hip/hip_runtime.h>
#include <hip/hip_bf16.h>

typedef __attribute__((ext_vector_type(8))) __bf16 bf16x8;
typedef __attribute__((ext_vector_type(4))) float f32x4;

#define DEV static __device__ __forceinline__

DEV void load_lds16(const void* g, void* l) {
  __builtin_amdgcn_global_load_lds(
      (const __attribute__((address_space(1))) unsigned int*)g,
      (__attribute__((address_space(3))) unsigned int*)l, 16, 0, 0);
}

DEV unsigned short bf16bits(float v) {
  __hip_bfloat16 h = __float2bfloat16(v);
  return __builtin_bit_cast(unsigned short, h);
}

struct Off2 { unsigned long long a[2], b[2], c[2]; };

enum { EPI_BF16 = 0, EPI_F32 = 1, EPI_LEAKY = 2 };
enum { MODE_PLAIN = 0, MODE_SCORES = 1, MODE_PV = 2 };

// C[M][N] = A[M][K] * BT[N][K]^T + bias ; 128x128 tile, BK=32, 4 waves, 4x4 MFMA/wave
template<int EPI, int MODE>
__global__ __launch_bounds__(256) void k_gemm(
    const unsigned short* __restrict__ Abase, long lda,
    const unsigned short* __restrict__ Bbase, long ldb,
    const float* __restrict__ bias,
    void* __restrict__ Cbase, long ldc,
    int M, int N, int K, Off2 off)
{
  const int z = blockIdx.z;
  const int m0 = blockIdx.y * 128, n0 = blockIdx.x * 128;
  if (MODE == MODE_SCORES && n0 > m0 + 127) return;
  const unsigned short* A = Abase + off.a[z];
  const unsigned short* B = Bbase + off.b[z];
  const int kmax = (MODE == MODE_PV) ? (K < m0 + 128 ? K : m0 + 128) : K;

  __shared__ unsigned short As[128 * 32];
  __shared__ unsigned short Bs[128 * 32];

  const int tid = threadIdx.x;
  const int l = tid & 63;
  const int wr = tid >> 7;          // wave row (0..1)
  const int wc = (tid >> 6) & 1;    // wave col (0..1)
  const int srow = tid >> 2;        // staging row 0..63
  const int scol = (tid & 3) << 3;  // staging col 0,8,16,24

  f32x4 acc[4][4] = {};

  const size_t aoff = (size_t)(m0 + srow) * lda + scol;
  const size_t boff = (size_t)(n0 + srow) * ldb + scol;

  for (int kk = 0; kk < kmax; kk += 32) {
    __syncthreads();
    load_lds16(A + aoff + kk,            &As[(size_t)tid * 8]);
    load_lds16(A + aoff + 64 * lda + kk, &As[2048 + (size_t)tid * 8]);
    load_lds16(B + boff + kk,            &Bs[(size_t)tid * 8]);
    load_lds16(B + boff + 64 * ldb + kk, &Bs[2048 + (size_t)tid * 8]);
    __syncthreads();

    const int kc = (l >> 4) << 3;
    const int rA = wr * 64 + (l & 15);
    const int rB = wc * 64 + (l & 15);
    bf16x8 af[4], bfr[4];
#pragma unroll
    for (int i = 0; i < 4; i++) {
      af[i]  = *(const bf16x8*)&As[(rA + i * 16) * 32 + kc];
      bfr[i] = *(const bf16x8*)&Bs[(rB + i * 16) * 32 + kc];
    }
#pragma unroll
    for (int mi = 0; mi < 4; mi++)
#pragma unroll
      for (int ni = 0; ni < 4; ni++)
        acc[mi][ni] = __builtin_amdgcn_mfma_f32_16x16x32_bf16(af[mi], bfr[ni], acc[mi][ni], 0, 0, 0);
  }

  const int r0 = m0 + wr * 64 + ((l >> 4) << 2);
  const int c0 = n0 + wc * 64 + (l & 15);
#pragma unroll
  for (int ni = 0; ni < 4; ni++) {
    const int col = c0 + ni * 16;
    const float bv = bias ? bias[col] : 0.f;
#pragma unroll
    for (int mi = 0; mi < 4; mi++) {
#pragma unroll
      for (int r = 0; r < 4; r++) {
        const int row = r0 + mi * 16 + r;
        float v = acc[mi][ni][r] + bv;
        const size_t ci = off.c[z] + (size_t)row * ldc + col;
        if (EPI == EPI_BF16) {
          ((unsigned short*)Cbase)[ci] = bf16bits(v);
        } else if (EPI == EPI_F32) {
          ((float*)Cbase)[ci] = v;
        } else {
          ((float*)Cbase)[ci] = v > 0.f ? v : 0.01f * v;
        }
      }
    }
  }
}

// x (f32) -> bf16, 4 elems/thread
__global__ __launch_bounds__(256) void k_cast_x(const float* __restrict__ in,
                                                unsigned short* __restrict__ out) {
  const size_t i = ((size_t)blockIdx.x * 256 + threadIdx.x) * 4;
  float4 v = *(const float4*)&in[i];
  ushort4 o;
  o.x = bf16bits(v.x); o.y = bf16bits(v.y); o.z = bf16bits(v.z); o.w = bf16bits(v.w);
  *(ushort4*)&out[i] = o;
}

// W[R][C] f32 -> WT[C][R] bf16
__global__ __launch_bounds__(256) void k_wt(const float* __restrict__ in,
                                            unsigned short* __restrict__ out,
                                            int R, int C) {
  __shared__ float tile[32][33];
  const int c0 = blockIdx.x * 32, r0 = blockIdx.y * 32;
  const int tx = threadIdx.x, ty = threadIdx.y;
#pragma unroll
  for (int k = 0; k < 4; k++)
    tile[ty + 8 * k][tx] = in[(size_t)(r0 + ty + 8 * k) * C + c0 + tx];
  __syncthreads();
#pragma unroll
  for (int k = 0; k < 4; k++)
    out[(size_t)(c0 + ty + 8 * k) * R + r0 + tx] = bf16bits(tile[tx][ty + 8 * k]);
}

// V[b*2048+s][h*768+d] -> Vt[(b*3+h)*768+d][s], bf16
__global__ __launch_bounds__(256) void k_tv(const unsigned short* __restrict__ V,
                                            unsigned short* __restrict__ Vt) {
  const int bh = blockIdx.z, b = bh / 3, h = bh % 3;
  const int s0 = blockIdx.x * 64, d0 = blockIdx.y * 64;
  __shared__ unsigned short tile[64][65];
  const int t = threadIdx.x;
  const int tr = t >> 4, tc4 = (t & 15) << 2;
  const unsigned short* src = V + (size_t)(b * 2048 + s0) * 2304 + h * 768 + d0;
#pragma unroll
  for (int p = 0; p < 4; p++) {
    int sr = p * 16 + tr;
    ushort4 v = *(const ushort4*)&src[(size_t)sr * 2304 + tc4];
    tile[sr][tc4] = v.x; tile[sr][tc4 + 1] = v.y; tile[sr][tc4 + 2] = v.z; tile[sr][tc4 + 3] = v.w;
  }
  __syncthreads();
  unsigned short* dst = Vt + (size_t)(bh * 768 + d0) * 2048 + s0;
#pragma unroll
  for (int p = 0; p < 4; p++) {
    int dr = p * 16 + tr;
    ushort4 v;
    v.x = tile[tc4][dr]; v.y = tile[tc4 + 1][dr]; v.z = tile[tc4 + 2][dr]; v.w = tile[tc4 + 3][dr];
    *(ushort4*)&dst[(size_t)dr * 2048 + tc4] = v;
  }
}

// causal row softmax: Sc f32 [z][2048][2048] -> P bf16, zeros above diagonal
__global__ __launch_bounds__(256) void k_softmax(const float* __restrict__ Sc,
                                                 unsigned short* __restrict__ P) {
  const int i = blockIdx.x;
  const size_t zoff = (size_t)blockIdx.y * 2048 * 2048;
  const float* srow = Sc + zoff + (size_t)i * 2048;
  unsigned short* prow = P + zoff + (size_t)i * 2048;
  const int t = threadIdx.x;
  float s[8];
  float mx = -1e30f;
#pragma unroll
  for (int j = 0; j < 8; j++) {
    int col = j * 256 + t;
    s[j] = (col <= i) ? srow[col] : -1e30f;
    mx = fmaxf(mx, s[j]);
  }
#pragma unroll
  for (int o = 32; o >= 1; o >>= 1) mx = fmaxf(mx, __shfl_xor(mx, o, 64));
  __shared__ float rmax[4], rsum[4];
  const int w = t >> 6;
  if ((t & 63) == 0) rmax[w] = mx;
  __syncthreads();
  mx = fmaxf(fmaxf(rmax[0], rmax[1]), fmaxf(rmax[2], rmax[3]));
  float sum = 0.f;
#pragma unroll
  for (int j = 0; j < 8; j++) {
    int col = j * 256 + t;
    float e = (col <= i) ? expf(s[j] - mx) : 0.f;
    s[j] = e;
    sum += e;
  }
#pragma unroll
  for (int o = 32; o >= 1; o >>= 1) sum += __shfl_xor(sum, o, 64);
  if ((t & 63) == 0) rsum[w] = sum;
  __syncthreads();
  sum = rsum[0] + rsum[1] + rsum[2] + rsum[3];
  const float inv = 1.f / sum;
#pragma unroll
  for (int j = 0; j < 8; j++) {
    int col = j * 256 + t;
    prow[col] = bf16bits(s[j] * inv);
  }
}

__global__ __launch_bounds__(256) void k_red1(const float* __restrict__ a,
                                              float* __restrict__ part) {
  float s = 0.f;
  for (size_t idx = (size_t)blockIdx.x * 256 + threadIdx.x; idx < 6291456ull; idx += 2048ull * 256)
    s += a[idx];
#pragma unroll
  for (int o = 32; o >= 1; o >>= 1) s += __shfl_xor(s, o, 64);
  __shared__ float r[4];
  const int t = threadIdx.x, w = t >> 6;
  if ((t & 63) == 0) r[w] = s;
  __syncthreads();
  if (t == 0) part[blockIdx.x] = r[0] + r[1] + r[2] + r[3];
}

__global__ __launch_bounds__(256) void k_red2(const float* __restrict__ part,
                                              float* __restrict__ mean) {
  const int t = threadIdx.x;
  float s = 0.f;
  for (int i = t; i < 2048; i += 256) s += part[i];
#pragma unroll
  for (int o = 32; o >= 1; o >>= 1) s += __shfl_xor(s, o, 64);
  __shared__ float r[4];
  const int w = t >> 6;
  if ((t & 63) == 0) r[w] = s;
  __syncthreads();
  if (t == 0) mean[0] = (r[0] + r[1] + r[2] + r[3]) * (1.f / 6291456.f);
}

__global__ __launch_bounds__(256) void k_residual(const float* __restrict__ a,
                                                  const float* __restrict__ x,
                                                  const float* __restrict__ meanp,
                                                  unsigned short* __restrict__ yb) {
  const float mean = meanp[0];
  const size_t i = ((size_t)blockIdx.x * 256 + threadIdx.x) * 4;
  float4 av = *(const float4*)&a[i];
  float4 xv = *(const float4*)&x[i];
  ushort4 o;
  o.x = bf16bits(av.x - mean + xv.x);
  o.y = bf16bits(av.y - mean + xv.y);
  o.z = bf16bits(av.z - mean + xv.z);
  o.w = bf16bits(av.w - mean + xv.w);
  *(ushort4*)&yb[i] = o;
}

extern "C" void kernel_launch(void* const* d_in, const int* in_sizes, int n_in,
                              void* d_out, int out_size, void* d_ws, size_t ws_size,
                              hipStream_t stream) {
  const float* x   = (const float*)d_in[0];
  const float* Wq  = (const float*)d_in[1];
  const float* bq  = (const float*)d_in[2];
  const float* Wk  = (const float*)d_in[3];
  const float* bk  = (const float*)d_in[4];
  const float* Wv  = (const float*)d_in[5];
  const float* bv  = (const float*)d_in[6];
  const float* Wo  = (const float*)d_in[7];
  const float* bo  = (const float*)d_in[8];
  const float* Wf  = (const float*)d_in[9];
  const float* bfb = (const float*)d_in[10];

  char* ws = (char*)d_ws;
  const size_t o_xb  = 0;                       // 8192*768*2  = 12,582,912
  const size_t o_Wqt = 12582912;                // each Wt 2304*768*2 = 3,538,944
  const size_t o_Wkt = o_Wqt + 3538944;
  const size_t o_Wvt = o_Wkt + 3538944;
  const size_t o_Wot = o_Wvt + 3538944;
  const size_t o_Wft = o_Wot + 3538944;         // 768*768*2 = 1,179,648
  const size_t o_Q   = o_Wft + 1179648;         // 8192*2304*2 = 37,748,736
  const size_t o_K   = o_Q + 37748736;
  const size_t o_V   = o_K + 37748736;
  const size_t o_Vt  = o_V + 37748736;
  const size_t o_O   = o_Vt + 37748736;
  const size_t o_Sc  = o_V;                     // reuse V after k_tv (33.5MB <= 37.7MB)
  const size_t o_P   = o_O + 37748736;          // 2*2048*2048*2 = 16,777,216
  const size_t o_a   = o_Q;                     // reuse Q after attention (25.2MB)
  const size_t o_yb  = o_K;                     // reuse K
  const size_t o_prt = o_P + 16777216;
  const size_t o_mn  = o_prt + 8192;
  if (ws_size < o_mn + 64) return;              // ws too small -> clean fail

  Off2 z0 = {{0, 0}, {0, 0}, {0, 0}};
  dim3 b32(32, 8);

  k_cast_x<<<6144, 256, 0, stream>>>(x, (unsigned short*)(ws + o_xb));
  k_wt<<<dim3(72, 24), b32, 0, stream>>>(Wq, (unsigned short*)(ws + o_Wqt), 768, 2304);
  k_wt<<<dim3(72, 24), b32, 0, stream>>>(Wk, (unsigned short*)(ws + o_Wkt), 768, 2304);
  k_wt<<<dim3(72, 24), b32, 0, stream>>>(Wv, (unsigned short*)(ws + o_Wvt), 768, 2304);
  k_wt<<<dim3(24, 72), b32, 0, stream>>>(Wo, (unsigned short*)(ws + o_Wot), 2304, 768);
  k_wt<<<dim3(24, 24), b32, 0, stream>>>(Wf, (unsigned short*)(ws + o_Wft), 768, 768);

  k_gemm<EPI_BF16, MODE_PLAIN><<<dim3(18, 64, 1), 256, 0, stream>>>(
      (const unsigned short*)(ws + o_xb), 768, (const unsigned short*)(ws + o_Wqt), 768, bq,
      ws + o_Q, 2304, 8192, 2304, 768, z0);
  k_gemm<EPI_BF16, MODE_PLAIN><<<dim3(18, 64, 1), 256, 0, stream>>>(
      (const unsigned short*)(ws + o_xb), 768, (const unsigned short*)(ws + o_Wkt), 768, bk,
      ws + o_K, 2304, 8192, 2304, 768, z0);
  k_gemm<EPI_BF16, MODE_PLAIN><<<dim3(18, 64, 1), 256, 0, stream>>>(
      (const unsigned short*)(ws + o_xb), 768, (const unsigned short*)(ws + o_Wvt), 768, bv,
      ws + o_V, 2304, 8192, 2304, 768, z0);

  k_tv<<<dim3(32, 12, 12), 256, 0, stream>>>((const unsigned short*)(ws + o_V),
                                             (unsigned short*)(ws + o_Vt));

  for (int c = 0; c < 6; c++) {
    Off2 so, po;
    for (int zz = 0; zz < 2; zz++) {
      int bh = 2 * c + zz, b = bh / 3, h = bh % 3;
      so.a[zz] = (size_t)b * 2048 * 2304 + (size_t)h * 768;
      so.b[zz] = so.a[zz];
      so.c[zz] = (size_t)zz * 2048 * 2048;
      po.a[zz] = (size_t)zz * 2048 * 2048;
      po.b[zz] = (size_t)bh * 768 * 2048;
      po.c[zz] = (size_t)b * 2048 * 2304 + (size_t)h * 768;
    }
    k_gemm<EPI_F32, MODE_SCORES><<<dim3(16, 16, 2), 256, 0, stream>>>(
        (const unsigned short*)(ws + o_Q), 2304, (const unsigned short*)(ws + o_K), 2304, nullptr,
        ws + o_Sc, 2048, 2048, 2048, 768, so);
    k_softmax<<<dim3(2048, 2), 256, 0, stream>>>((const float*)(ws + o_Sc),
                                                 (unsigned short*)(ws + o_P));
    k_gemm<EPI_BF16, MODE_PV><<<dim3(6, 16, 2), 256, 0, stream>>>(
        (const unsigned short*)(ws + o_P), 2048, (const unsigned short*)(ws + o_Vt), 2048, nullptr,
        ws + o_O, 2304, 2048, 768, 2048, po);
  }

  k_gemm<EPI_F32, MODE_PLAIN><<<dim3(6, 64, 1), 256, 0, stream>>>(
      (const unsigned short*)(ws + o_O), 2304, (const unsigned short*)(ws + o_Wot), 2304, bo,
      ws + o_a, 768, 8192, 768, 2304, z0);

  k_red1<<<2048, 256, 0, stream>>>((const float*)(ws + o_a), (float*)(ws + o_prt));
  k_red2<<<1, 256, 0, stream>>>((const float*)(ws + o_prt), (float*)(ws + o_mn));
  k_residual<<<6144, 256, 0, stream>>>((const float*)(ws + o_a), x,
                                       (const float*)(ws + o_mn), (unsigned short*)(ws + o_yb));

  k_gemm<EPI_LEAKY, MODE_PLAIN><<<dim3(6, 64, 1), 256, 0, stream>>>(
      (const unsigned short*)(ws + o_yb), 768, (const unsigned short*)(ws + o_Wft), 768, bfb,
      d_out, 768, 8192, 768, 768, z0);
}

// Round 2
// 665.582 us; speedup vs baseline: 1.1789x; 1.1789x over previous
//
#include <hip/hip_runtime.h>
#include <hip/hip_bf16.h>

typedef __attribute__((ext_vector_type(8))) __bf16 bf16x8;
typedef __attribute__((ext_vector_type(4))) float f32x4;

#define DEV static __device__ __forceinline__

DEV void load_lds16(const void* g, void* l) {
  __builtin_amdgcn_global_load_lds(
      (const __attribute__((address_space(1))) unsigned int*)g,
      (__attribute__((address_space(3))) unsigned int*)l, 16, 0, 0);
}

DEV unsigned short bf16bits(float v) {
  __hip_bfloat16 h = __float2bfloat16(v);
  return __builtin_bit_cast(unsigned short, h);
}

struct OffN { unsigned long long a[12], b[12], c[12]; };

enum { EPI_BF16 = 0, EPI_F32 = 1, EPI_LEAKY = 2, EPI_QKV = 3 };
enum { MODE_PLAIN = 0, MODE_SCORES = 1, MODE_PV = 2 };

// C[M][N] = A[M][K] * BT[N][K]^T + bias ; 128x128 tile, BK=32, 4 waves, 4x4 MFMA/wave
template<int EPI, int MODE>
__global__ __launch_bounds__(256) void k_gemm(
    const unsigned short* __restrict__ Abase, long lda,
    const unsigned short* __restrict__ Bbase, long ldb,
    const float* __restrict__ bias,
    void* __restrict__ Cbase, long ldc,
    int M, int N, int K, OffN off)
{
  const int z = blockIdx.z;
  const int m0 = blockIdx.y * 128, n0 = blockIdx.x * 128;
  if (MODE == MODE_SCORES && n0 > m0 + 127) return;
  const unsigned short* A = Abase + off.a[z];
  const unsigned short* B = Bbase + off.b[z];
  const int kmax = (MODE == MODE_PV) ? (K < m0 + 128 ? K : m0 + 128) : K;

  __shared__ unsigned short As[128 * 32];
  __shared__ unsigned short Bs[128 * 32];

  const int tid = threadIdx.x;
  const int l = tid & 63;
  const int wr = tid >> 7;          // wave row (0..1)
  const int wc = (tid >> 6) & 1;    // wave col (0..1)
  const int srow = tid >> 2;        // staging row 0..63
  const int scol = (tid & 3) << 3;  // staging col 0,8,16,24

  f32x4 acc[4][4] = {};

  const size_t aoff = (size_t)(m0 + srow) * lda + scol;
  const size_t boff = (size_t)(n0 + srow) * ldb + scol;

  for (int kk = 0; kk < kmax; kk += 32) {
    __syncthreads();
    load_lds16(A + aoff + kk,            &As[(size_t)tid * 8]);
    load_lds16(A + aoff + 64 * lda + kk, &As[2048 + (size_t)tid * 8]);
    load_lds16(B + boff + kk,            &Bs[(size_t)tid * 8]);
    load_lds16(B + boff + 64 * ldb + kk, &Bs[2048 + (size_t)tid * 8]);
    __syncthreads();

    const int kc = (l >> 4) << 3;
    const int rA = wr * 64 + (l & 15);
    const int rB = wc * 64 + (l & 15);
    bf16x8 af[4], bfr[4];
#pragma unroll
    for (int i = 0; i < 4; i++) {
      af[i]  = *(const bf16x8*)&As[(rA + i * 16) * 32 + kc];
      bfr[i] = *(const bf16x8*)&Bs[(rB + i * 16) * 32 + kc];
    }
#pragma unroll
    for (int mi = 0; mi < 4; mi++)
#pragma unroll
      for (int ni = 0; ni < 4; ni++)
        acc[mi][ni] = __builtin_amdgcn_mfma_f32_16x16x32_bf16(af[mi], bfr[ni], acc[mi][ni], 0, 0, 0);
  }

  const int r0 = m0 + wr * 64 + ((l >> 4) << 2);
  const int c0 = n0 + wc * 64 + (l & 15);
#pragma unroll
  for (int ni = 0; ni < 4; ni++) {
    const int col = c0 + ni * 16;
    const float bv = bias ? bias[col] : 0.f;
#pragma unroll
    for (int mi = 0; mi < 4; mi++) {
#pragma unroll
      for (int r = 0; r < 4; r++) {
        const int row = r0 + mi * 16 + r;
        float v = acc[mi][ni][r] + bv;
        if (EPI == EPI_QKV) {
          // col in [0,6912): demux into contiguous [3][8192][2304]
          const int sel = col >= 4608 ? 2 : (col >= 2304 ? 1 : 0);
          const size_t ci = (size_t)sel * (8192ull * 2304) + (size_t)row * 2304 + (col - sel * 2304);
          ((unsigned short*)Cbase)[ci] = bf16bits(v);
        } else {
          const size_t ci = off.c[z] + (size_t)row * ldc + col;
          if (EPI == EPI_BF16) {
            ((unsigned short*)Cbase)[ci] = bf16bits(v);
          } else if (EPI == EPI_F32) {
            ((float*)Cbase)[ci] = v;
          } else {
            ((float*)Cbase)[ci] = v > 0.f ? v : 0.01f * v;
          }
        }
      }
    }
  }
}

// x (f32) -> bf16, 4 elems/thread
__global__ __launch_bounds__(256) void k_cast_x(const float* __restrict__ in,
                                                unsigned short* __restrict__ out) {
  const size_t i = ((size_t)blockIdx.x * 256 + threadIdx.x) * 4;
  float4 v = *(const float4*)&in[i];
  ushort4 o;
  o.x = bf16bits(v.x); o.y = bf16bits(v.y); o.z = bf16bits(v.z); o.w = bf16bits(v.w);
  *(ushort4*)&out[i] = o;
}

// W[R][C] f32 -> WT[C][R] bf16
__global__ __launch_bounds__(256) void k_wt(const float* __restrict__ in,
                                            unsigned short* __restrict__ out,
                                            int R, int C) {
  __shared__ float tile[32][33];
  const int c0 = blockIdx.x * 32, r0 = blockIdx.y * 32;
  const int tx = threadIdx.x, ty = threadIdx.y;
#pragma unroll
  for (int k = 0; k < 4; k++)
    tile[ty + 8 * k][tx] = in[(size_t)(r0 + ty + 8 * k) * C + c0 + tx];
  __syncthreads();
#pragma unroll
  for (int k = 0; k < 4; k++)
    out[(size_t)(c0 + ty + 8 * k) * R + r0 + tx] = bf16bits(tile[tx][ty + 8 * k]);
}

__global__ __launch_bounds__(256) void k_bias_concat(const float* __restrict__ bq,
                                                     const float* __restrict__ bk,
                                                     const float* __restrict__ bv,
                                                     float* __restrict__ out) {
  const int i = blockIdx.x * 256 + threadIdx.x;
  if (i < 2304) out[i] = bq[i];
  else if (i < 4608) out[i] = bk[i - 2304];
  else if (i < 6912) out[i] = bv[i - 4608];
}

// V[b*2048+s][h*768+d] -> Vt[(b*3+h)*768+d][s], bf16
__global__ __launch_bounds__(256) void k_tv(const unsigned short* __restrict__ V,
                                            unsigned short* __restrict__ Vt) {
  const int bh = blockIdx.z, b = bh / 3, h = bh % 3;
  const int s0 = blockIdx.x * 64, d0 = blockIdx.y * 64;
  __shared__ unsigned short tile[64][65];
  const int t = threadIdx.x;
  const int tr = t >> 4, tc4 = (t & 15) << 2;
  const unsigned short* src = V + (size_t)(b * 2048 + s0) * 2304 + h * 768 + d0;
#pragma unroll
  for (int p = 0; p < 4; p++) {
    int sr = p * 16 + tr;
    ushort4 v = *(const ushort4*)&src[(size_t)sr * 2304 + tc4];
    tile[sr][tc4] = v.x; tile[sr][tc4 + 1] = v.y; tile[sr][tc4 + 2] = v.z; tile[sr][tc4 + 3] = v.w;
  }
  __syncthreads();
  unsigned short* dst = Vt + (size_t)(bh * 768 + d0) * 2048 + s0;
#pragma unroll
  for (int p = 0; p < 4; p++) {
    int dr = p * 16 + tr;
    ushort4 v;
    v.x = tile[tc4][dr]; v.y = tile[tc4 + 1][dr]; v.z = tile[tc4 + 2][dr]; v.w = tile[tc4 + 3][dr];
    *(ushort4*)&dst[(size_t)dr * 2048 + tc4] = v;
  }
}

// causal row softmax IN PLACE: Sc f32 row i (stride 2048 f32) -> P bf16 row i
// (stride 4096 ushort, overlaying the same bytes). Reads cols<=i, writes
// zeros up to the 128-tile boundary kb.
__global__ __launch_bounds__(256) void k_softmax(float* __restrict__ Sc) {
  const int i = blockIdx.x;
  const size_t zo = (size_t)blockIdx.y * 2048 * 2048;
  float* srow = Sc + zo + (size_t)i * 2048;
  unsigned short* prow = (unsigned short*)Sc + zo * 2 + (size_t)i * 4096;
  const int t = threadIdx.x;
  const int kb = ((i >> 7) + 1) << 7;  // cols [0,kb) must be written
  float s[8];
  float mx = -1e30f;
#pragma unroll
  for (int j = 0; j < 8; j++) {
    const int col = j * 256 + t;
    const bool act = (j << 8) < kb;
    s[j] = (act && col <= i) ? srow[col] : -1e30f;
    mx = fmaxf(mx, s[j]);
  }
#pragma unroll
  for (int o = 32; o >= 1; o >>= 1) mx = fmaxf(mx, __shfl_xor(mx, o, 64));
  __shared__ float rmax[4], rsum[4];
  const int w = t >> 6;
  if ((t & 63) == 0) rmax[w] = mx;
  __syncthreads();   // also orders all reads of srow before any P write below
  mx = fmaxf(fmaxf(rmax[0], rmax[1]), fmaxf(rmax[2], rmax[3]));
  float sum = 0.f;
#pragma unroll
  for (int j = 0; j < 8; j++) {
    const int col = j * 256 + t;
    const float e = (((j << 8) < kb) && col <= i) ? expf(s[j] - mx) : 0.f;
    s[j] = e;
    sum += e;
  }
#pragma unroll
  for (int o = 32; o >= 1; o >>= 1) sum += __shfl_xor(sum, o, 64);
  if ((t & 63) == 0) rsum[w] = sum;
  __syncthreads();
  sum = rsum[0] + rsum[1] + rsum[2] + rsum[3];
  const float inv = 1.f / sum;
#pragma unroll
  for (int j = 0; j < 8; j++) {
    const int col = j * 256 + t;
    if (((j << 8) < kb) && col < kb) prow[col] = bf16bits(s[j] * inv);
  }
}

__global__ __launch_bounds__(256) void k_red1(const float* __restrict__ a,
                                              float* __restrict__ part) {
  float s = 0.f;
  for (size_t idx = (size_t)blockIdx.x * 256 + threadIdx.x; idx < 6291456ull; idx += 2048ull * 256)
    s += a[idx];
#pragma unroll
  for (int o = 32; o >= 1; o >>= 1) s += __shfl_xor(s, o, 64);
  __shared__ float r[4];
  const int t = threadIdx.x, w = t >> 6;
  if ((t & 63) == 0) r[w] = s;
  __syncthreads();
  if (t == 0) part[blockIdx.x] = r[0] + r[1] + r[2] + r[3];
}

__global__ __launch_bounds__(256) void k_red2(const float* __restrict__ part,
                                              float* __restrict__ mean) {
  const int t = threadIdx.x;
  float s = 0.f;
  for (int i = t; i < 2048; i += 256) s += part[i];
#pragma unroll
  for (int o = 32; o >= 1; o >>= 1) s += __shfl_xor(s, o, 64);
  __shared__ float r[4];
  const int w = t >> 6;
  if ((t & 63) == 0) r[w] = s;
  __syncthreads();
  if (t == 0) mean[0] = (r[0] + r[1] + r[2] + r[3]) * (1.f / 6291456.f);
}

__global__ __launch_bounds__(256) void k_residual(const float* __restrict__ a,
                                                  const float* __restrict__ x,
                                                  const float* __restrict__ meanp,
                                                  unsigned short* __restrict__ yb) {
  const float mean = meanp[0];
  const size_t i = ((size_t)blockIdx.x * 256 + threadIdx.x) * 4;
  float4 av = *(const float4*)&a[i];
  float4 xv = *(const float4*)&x[i];
  ushort4 o;
  o.x = bf16bits(av.x - mean + xv.x);
  o.y = bf16bits(av.y - mean + xv.y);
  o.z = bf16bits(av.z - mean + xv.z);
  o.w = bf16bits(av.w - mean + xv.w);
  *(ushort4*)&yb[i] = o;
}

extern "C" void kernel_launch(void* const* d_in, const int* in_sizes, int n_in,
                              void* d_out, int out_size, void* d_ws, size_t ws_size,
                              hipStream_t stream) {
  const float* x   = (const float*)d_in[0];
  const float* Wq  = (const float*)d_in[1];
  const float* bq  = (const float*)d_in[2];
  const float* Wk  = (const float*)d_in[3];
  const float* bk  = (const float*)d_in[4];
  const float* Wv  = (const float*)d_in[5];
  const float* bv  = (const float*)d_in[6];
  const float* Wo  = (const float*)d_in[7];
  const float* bo  = (const float*)d_in[8];
  const float* Wf  = (const float*)d_in[9];
  const float* bfb = (const float*)d_in[10];

  char* ws = (char*)d_ws;
  const size_t o_xb  = 0;                          // 8192*768*2       = 12,582,912
  const size_t o_Wqkvt = 12582912;                 // 6912*768*2       = 10,616,832
  const size_t o_Wot = o_Wqkvt + 10616832;         // 2304*768*2 f/bf  =  3,538,944
  const size_t o_Wft = o_Wot + 3538944;            // 768*768*2        =  1,179,648
  const size_t o_bqkv = o_Wft + 1179648;           // 6912*4 -> pad 32K
  const size_t o_prt = o_bqkv + 32768;
  const size_t o_mn  = o_prt + 8192;
  const size_t o_Q   = o_mn + 128;                 // Q,K,V contiguous (QKV demux)
  const size_t MSZ   = 37748736;                   // 8192*2304*2
  const size_t o_K   = o_Q + MSZ;
  const size_t o_V   = o_K + MSZ;
  const size_t o_Vt  = o_V + MSZ;
  const size_t o_O   = o_Vt + MSZ;
  const size_t o_end = o_O + MSZ;                  // ~216.7 MB
  const size_t SC1   = 16777216;                   // 2048*2048*4 per head
  if (ws_size < o_end) return;

  // scores/P buffer: prefer after o_end, many heads per chunk; else overlay V
  size_t o_Sc; int hpc;
  {
    size_t avail = ws_size - o_end;
    hpc = (int)(avail / SC1); if (hpc > 12) hpc = 12;
    if (hpc >= 2) { o_Sc = o_end; }
    else { o_Sc = o_V; hpc = 2; }  // 2*16.78MB fits in V's 37.75MB (V dead after k_tv)
  }

  const size_t o_a  = o_Q;   // f32 8192*768 (Q dead after attention)
  const size_t o_yb = o_K;   // bf16 8192*768 (K dead after attention)

  OffN z0{};
  dim3 b32(32, 8);

  k_cast_x<<<6144, 256, 0, stream>>>(x, (unsigned short*)(ws + o_xb));
  k_wt<<<dim3(72, 24), b32, 0, stream>>>(Wq, (unsigned short*)(ws + o_Wqkvt), 768, 2304);
  k_wt<<<dim3(72, 24), b32, 0, stream>>>(Wk, (unsigned short*)(ws + o_Wqkvt) + 2304 * 768, 768, 2304);
  k_wt<<<dim3(72, 24), b32, 0, stream>>>(Wv, (unsigned short*)(ws + o_Wqkvt) + 2 * 2304 * 768, 768, 2304);
  k_wt<<<dim3(24, 72), b32, 0, stream>>>(Wo, (unsigned short*)(ws + o_Wot), 2304, 768);
  k_wt<<<dim3(24, 24), b32, 0, stream>>>(Wf, (unsigned short*)(ws + o_Wft), 768, 768);
  k_bias_concat<<<27, 256, 0, stream>>>(bq, bk, bv, (float*)(ws + o_bqkv));

  // fused QKV: [8192,768] x [6912,768]^T -> demuxed into Q|K|V
  k_gemm<EPI_QKV, MODE_PLAIN><<<dim3(54, 64, 1), 256, 0, stream>>>(
      (const unsigned short*)(ws + o_xb), 768, (const unsigned short*)(ws + o_Wqkvt), 768,
      (const float*)(ws + o_bqkv), ws + o_Q, 2304, 8192, 6912, 768, z0);

  k_tv<<<dim3(32, 12, 12), 256, 0, stream>>>((const unsigned short*)(ws + o_V),
                                             (unsigned short*)(ws + o_Vt));

  for (int h0 = 0; h0 < 12; h0 += hpc) {
    const int cnt = (12 - h0) < hpc ? (12 - h0) : hpc;
    OffN so{}, po{};
    for (int zz = 0; zz < cnt; zz++) {
      const int bh = h0 + zz, b = bh / 3, h = bh % 3;
      so.a[zz] = (size_t)b * 2048 * 2304 + (size_t)h * 768;
      so.b[zz] = so.a[zz];
      so.c[zz] = (size_t)zz * 2048 * 2048;            // f32 elems
      po.a[zz] = (size_t)zz * 2048 * 2048 * 2;        // ushort elems (P overlay)
      po.b[zz] = (size_t)bh * 768 * 2048;
      po.c[zz] = (size_t)b * 2048 * 2304 + (size_t)h * 768;
    }
    k_gemm<EPI_F32, MODE_SCORES><<<dim3(16, 16, cnt), 256, 0, stream>>>(
        (const unsigned short*)(ws + o_Q), 2304, (const unsigned short*)(ws + o_K), 2304, nullptr,
        ws + o_Sc, 2048, 2048, 2048, 768, so);
    k_softmax<<<dim3(2048, cnt), 256, 0, stream>>>((float*)(ws + o_Sc));
    k_gemm<EPI_BF16, MODE_PV><<<dim3(6, 16, cnt), 256, 0, stream>>>(
        (const unsigned short*)(ws + o_Sc), 4096, (const unsigned short*)(ws + o_Vt), 2048, nullptr,
        ws + o_O, 2304, 2048, 768, 2048, po);
  }

  k_gemm<EPI_F32, MODE_PLAIN><<<dim3(6, 64, 1), 256, 0, stream>>>(
      (const unsigned short*)(ws + o_O), 2304, (const unsigned short*)(ws + o_Wot), 2304, bo,
      ws + o_a, 768, 8192, 768, 2304, z0);

  k_red1<<<2048, 256, 0, stream>>>((const float*)(ws + o_a), (float*)(ws + o_prt));
  k_red2<<<1, 256, 0, stream>>>((const float*)(ws + o_prt), (float*)(ws + o_mn));
  k_residual<<<6144, 256, 0, stream>>>((const float*)(ws + o_a), x,
                                       (const float*)(ws + o_mn), (unsigned short*)(ws + o_yb));

  k_gemm<EPI_LEAKY, MODE_PLAIN><<<dim3(6, 64, 1), 256, 0, stream>>>(
      (const unsigned short*)(ws + o_yb), 768, (const unsigned short*)(ws + o_Wft), 768, bfb,
      d_out, 768, 8192, 768, 768, z0);
}